// Round 1
// baseline (1054.260 us; speedup 1.0000x reference)
//
#include <hip/hip_runtime.h>
#include <cstdint>
#include <cstddef>

#define Bsz 8192
#define INsz 1024
#define Hsz 2048
#define Kxh 3072   // IN + H

typedef __attribute__((ext_vector_type(8))) short bf16x8;
typedef __attribute__((ext_vector_type(4))) float f32x4;

__device__ __forceinline__ unsigned short f2bf(float f) {
  unsigned int u = __float_as_uint(f);
  u += 0x7FFFu + ((u >> 16) & 1u);   // round-to-nearest-even
  return (unsigned short)(u >> 16);
}

__device__ __forceinline__ void gload_lds16(const void* g, void* l) {
  __builtin_amdgcn_global_load_lds(
      (const __attribute__((address_space(1))) void*)g,
      (__attribute__((address_space(3))) void*)l, 16, 0, 0);
}

__device__ __forceinline__ float fsigmoid(float x) { return 1.f / (1.f + __expf(-x)); }
__device__ __forceinline__ float ftanh(float x) {
  float ax = fabsf(x);
  float t = __expf(-2.f * ax);
  float r = (1.f - t) / (1.f + t);
  return copysignf(r, x);
}

// ---------------- conversion: xh = concat(x, h) as bf16 [8192][3072] ----------------
__global__ void convert_xh_kernel(const float* __restrict__ x,
                                  const float* __restrict__ h,
                                  unsigned short* __restrict__ xh) {
  int chunk = blockIdx.x * 256 + threadIdx.x;          // 3,145,728 chunks of 8
  int row = chunk / 384;
  int c8 = (chunk - row * 384) * 8;
  const float* src = (c8 < INsz) ? (x + (size_t)row * INsz + c8)
                                 : (h + (size_t)row * Hsz + (c8 - INsz));
  f32x4 v0 = *(const f32x4*)src;
  f32x4 v1 = *(const f32x4*)(src + 4);
  bf16x8 o;
  o[0] = (short)f2bf(v0[0]); o[1] = (short)f2bf(v0[1]);
  o[2] = (short)f2bf(v0[2]); o[3] = (short)f2bf(v0[3]);
  o[4] = (short)f2bf(v1[0]); o[5] = (short)f2bf(v1[1]);
  o[6] = (short)f2bf(v1[2]); o[7] = (short)f2bf(v1[3]);
  *(bf16x8*)(xh + (size_t)chunk * 8) = o;
}

// ---------------- transpose + convert: W[K][N] f32 -> WT[N][K] bf16 ----------------
__global__ void transpose_conv_kernel(const float* __restrict__ W,
                                      unsigned short* __restrict__ WT,
                                      int K, int N) {
  __shared__ float tile[32][33];
  const size_t moff = (size_t)blockIdx.z * (size_t)K * N;
  const float* Wg = W + moff;
  unsigned short* WTg = WT + moff;
  int n0 = blockIdx.x * 32;
  int k0 = blockIdx.y * 32;
  int tx = threadIdx.x, ty = threadIdx.y;              // (32, 8)
  #pragma unroll
  for (int j = 0; j < 4; ++j)
    tile[ty + j * 8][tx] = Wg[(size_t)(k0 + ty + j * 8) * N + n0 + tx];
  __syncthreads();
  #pragma unroll
  for (int j = 0; j < 4; ++j)
    WTg[(size_t)(n0 + ty + j * 8) * K + k0 + tx] = f2bf(tile[tx][ty + j * 8]);
}

// ---------------- fused LSTM GEMM ----------------
// Block computes a 128x128 output tile. 4 waves, each 64x64 (4x4 frags of 16x16).
// LDS tiles: A [128][64] bf16, Bt [128][64] bf16 (B^T layout, rows = output cols).
__device__ __forceinline__ void gemm_pass(
    const unsigned short* __restrict__ A,   // block A base (tile row 0, k 0), ld = Kxh
    const unsigned short* __restrict__ Bt,  // block B^T base (tile col 0, k 0)
    int ldb, int K,
    short* lA, short* lB,
    int tid, int lane, int wr, int wc,
    f32x4 (&acc)[4][4])
{
  const int il = lane & 15;
  const int kl = (lane >> 4) * 8;
  for (int k0 = 0; k0 < K; k0 += 64) {
    #pragma unroll
    for (int c = 0; c < 4; ++c) {
      int ch = c * 256 + tid;                 // 1024 chunks of 16B = 16KB A tile
      int row = ch >> 3;
      int col = (ch & 7) * 8;
      gload_lds16(A + (size_t)row * Kxh + k0 + col, lA + ch * 8);
    }
    #pragma unroll
    for (int c = 0; c < 4; ++c) {
      int ch = c * 256 + tid;
      int row = ch >> 3;
      int col = (ch & 7) * 8;
      gload_lds16(Bt + (size_t)row * ldb + k0 + col, lB + ch * 8);
    }
    __syncthreads();                          // drains vmcnt (compiler-inserted)
    #pragma unroll
    for (int ks = 0; ks < 2; ++ks) {
      bf16x8 a[4], b[4];
      #pragma unroll
      for (int m = 0; m < 4; ++m)
        a[m] = *(const bf16x8*)&lA[(wr * 64 + m * 16 + il) * 64 + ks * 32 + kl];
      #pragma unroll
      for (int n = 0; n < 4; ++n)
        b[n] = *(const bf16x8*)&lB[(wc * 64 + n * 16 + il) * 64 + ks * 32 + kl];
      #pragma unroll
      for (int m = 0; m < 4; ++m)
        #pragma unroll
        for (int n = 0; n < 4; ++n)
          acc[m][n] = __builtin_amdgcn_mfma_f32_16x16x32_bf16(a[m], b[n], acc[m][n], 0, 0, 0);
    }
    __syncthreads();
  }
}

__global__ __launch_bounds__(256, 2) void lstm_fused_kernel(
    const unsigned short* __restrict__ xh,    // [8192][3072] bf16
    const unsigned short* __restrict__ WgT,   // [4][2048][3072] bf16 (transposed)
    const unsigned short* __restrict__ WrT,   // [2048][1024] bf16 (transposed)
    const float* __restrict__ c_prev,         // [8192][2048]
    const float* __restrict__ b_gates,        // [4][2048]
    const float* __restrict__ b_res,          // [2048]
    float* __restrict__ h_out,
    float* __restrict__ c_out)
{
  __shared__ alignas(16) short lA[128 * 64];
  __shared__ alignas(16) short lB[128 * 64];
  const int tid = threadIdx.x;
  const int lane = tid & 63;
  const int wid = tid >> 6;
  const int wr = wid >> 1, wc = wid & 1;
  const int brow = (blockIdx.x >> 4) * 128;   // 64 row blocks
  const int bcol = (blockIdx.x & 15) * 128;   // 16 col blocks

  const unsigned short* Ab = xh + (size_t)brow * Kxh;
  const int col0 = bcol + wc * 64 + (lane & 15);            // + n*16
  const int row0 = brow + wr * 64 + ((lane >> 4) << 2);     // + m*16 + r

  const f32x4 zf = {0.f, 0.f, 0.f, 0.f};
  f32x4 acc[4][4];
  f32x4 C[4][4];   // running cell state, later reused as h partial
  f32x4 I[4][4];

  // ---- pass 1: forget gate (g=1): C = sigmoid(f)*c_prev ----
  #pragma unroll
  for (int m = 0; m < 4; ++m)
    #pragma unroll
    for (int n = 0; n < 4; ++n) acc[m][n] = zf;
  gemm_pass(Ab, WgT + (size_t)(1 * Hsz + bcol) * Kxh, Kxh, Kxh, lA, lB, tid, lane, wr, wc, acc);
  #pragma unroll
  for (int n = 0; n < 4; ++n) {
    float bgn = b_gates[1 * Hsz + col0 + n * 16];
    #pragma unroll
    for (int m = 0; m < 4; ++m)
      #pragma unroll
      for (int r = 0; r < 4; ++r) {
        float f = fsigmoid(acc[m][n][r] + bgn);
        C[m][n][r] = f * c_prev[(size_t)(row0 + m * 16 + r) * Hsz + col0 + n * 16];
      }
  }

  // ---- pass 2: input gate (g=0): I = sigmoid(i) ----
  #pragma unroll
  for (int m = 0; m < 4; ++m)
    #pragma unroll
    for (int n = 0; n < 4; ++n) acc[m][n] = zf;
  gemm_pass(Ab, WgT + (size_t)(0 * Hsz + bcol) * Kxh, Kxh, Kxh, lA, lB, tid, lane, wr, wc, acc);
  #pragma unroll
  for (int n = 0; n < 4; ++n) {
    float bgn = b_gates[0 * Hsz + col0 + n * 16];
    #pragma unroll
    for (int m = 0; m < 4; ++m)
      #pragma unroll
      for (int r = 0; r < 4; ++r)
        I[m][n][r] = fsigmoid(acc[m][n][r] + bgn);
  }

  // ---- pass 3: c_hat (g=3): C += I*tanh(chat); write c_out; C <- tanh(C) ----
  #pragma unroll
  for (int m = 0; m < 4; ++m)
    #pragma unroll
    for (int n = 0; n < 4; ++n) acc[m][n] = zf;
  gemm_pass(Ab, WgT + (size_t)(3 * Hsz + bcol) * Kxh, Kxh, Kxh, lA, lB, tid, lane, wr, wc, acc);
  #pragma unroll
  for (int n = 0; n < 4; ++n) {
    float bgn = b_gates[3 * Hsz + col0 + n * 16];
    #pragma unroll
    for (int m = 0; m < 4; ++m)
      #pragma unroll
      for (int r = 0; r < 4; ++r) {
        float ct = C[m][n][r] + I[m][n][r] * ftanh(acc[m][n][r] + bgn);
        c_out[(size_t)(row0 + m * 16 + r) * Hsz + col0 + n * 16] = ct;
        C[m][n][r] = ftanh(ct);
      }
  }

  // ---- pass 4: output gate (g=2): C <- sigmoid(o)*tanh(c_t) ----
  #pragma unroll
  for (int m = 0; m < 4; ++m)
    #pragma unroll
    for (int n = 0; n < 4; ++n) acc[m][n] = zf;
  gemm_pass(Ab, WgT + (size_t)(2 * Hsz + bcol) * Kxh, Kxh, Kxh, lA, lB, tid, lane, wr, wc, acc);
  #pragma unroll
  for (int n = 0; n < 4; ++n) {
    float bgn = b_gates[2 * Hsz + col0 + n * 16];
    #pragma unroll
    for (int m = 0; m < 4; ++m)
      #pragma unroll
      for (int r = 0; r < 4; ++r)
        C[m][n][r] = fsigmoid(acc[m][n][r] + bgn) * C[m][n][r];
  }

  // ---- pass 5: residual (K=1024): h = o*tanh(c) + x@W_res + b_res ----
  #pragma unroll
  for (int m = 0; m < 4; ++m)
    #pragma unroll
    for (int n = 0; n < 4; ++n) acc[m][n] = zf;
  gemm_pass(Ab, WrT + (size_t)bcol * INsz, INsz, INsz, lA, lB, tid, lane, wr, wc, acc);
  #pragma unroll
  for (int n = 0; n < 4; ++n) {
    float brn = b_res[col0 + n * 16];
    #pragma unroll
    for (int m = 0; m < 4; ++m)
      #pragma unroll
      for (int r = 0; r < 4; ++r)
        h_out[(size_t)(row0 + m * 16 + r) * Hsz + col0 + n * 16] =
            C[m][n][r] + acc[m][n][r] + brn;
  }
}

extern "C" void kernel_launch(void* const* d_in, const int* in_sizes, int n_in,
                              void* d_out, int out_size, void* d_ws, size_t ws_size,
                              hipStream_t stream) {
  const float* x  = (const float*)d_in[0];
  const float* h  = (const float*)d_in[1];
  const float* c  = (const float*)d_in[2];
  const float* Wg = (const float*)d_in[3];
  const float* bg = (const float*)d_in[4];
  const float* Wr = (const float*)d_in[5];
  const float* br = (const float*)d_in[6];
  float* out = (float*)d_out;

  char* ws = (char*)d_ws;
  unsigned short* xh  = (unsigned short*)ws;                       // 50,331,648 B
  unsigned short* WgT = (unsigned short*)(ws + 50331648);          // 50,331,648 B
  unsigned short* WrT = (unsigned short*)(ws + 100663296);         //  4,194,304 B

  convert_xh_kernel<<<12288, 256, 0, stream>>>(x, h, xh);
  transpose_conv_kernel<<<dim3(64, 96, 4), dim3(32, 8), 0, stream>>>(Wg, WgT, Kxh, Hsz);
  transpose_conv_kernel<<<dim3(64, 32, 1), dim3(32, 8), 0, stream>>>(Wr, WrT, INsz, Hsz);

  lstm_fused_kernel<<<1024, 256, 0, stream>>>(
      xh, WgT, WrT, c, bg, br, out, out + (size_t)Bsz * Hsz);
}

// Round 2
// 1010.571 us; speedup vs baseline: 1.0432x; 1.0432x over previous
//
#include <hip/hip_runtime.h>
#include <cstdint>
#include <cstddef>

#define Bsz 8192
#define INsz 1024
#define Hsz 2048
#define Kxh 3072   // IN + H

typedef __attribute__((ext_vector_type(8))) short bf16x8;
typedef __attribute__((ext_vector_type(4))) float f32x4;

__device__ __forceinline__ unsigned short f2bf(float f) {
  unsigned int u = __float_as_uint(f);
  u += 0x7FFFu + ((u >> 16) & 1u);   // round-to-nearest-even
  return (unsigned short)(u >> 16);
}

__device__ __forceinline__ void gload_lds16(const void* g, void* l) {
  __builtin_amdgcn_global_load_lds(
      (const __attribute__((address_space(1))) void*)g,
      (__attribute__((address_space(3))) void*)l, 16, 0, 0);
}

__device__ __forceinline__ float fsigmoid(float x) { return 1.f / (1.f + __expf(-x)); }
__device__ __forceinline__ float ftanh(float x) {
  float ax = fabsf(x);
  float t = __expf(-2.f * ax);
  float r = (1.f - t) / (1.f + t);
  return copysignf(r, x);
}

// ---------------- conversion: xh = concat(x, h) as bf16 [8192][3072] ----------------
__global__ void convert_xh_kernel(const float* __restrict__ x,
                                  const float* __restrict__ h,
                                  unsigned short* __restrict__ xh) {
  int chunk = blockIdx.x * 256 + threadIdx.x;          // 3,145,728 chunks of 8
  int row = chunk / 384;
  int c8 = (chunk - row * 384) * 8;
  const float* src = (c8 < INsz) ? (x + (size_t)row * INsz + c8)
                                 : (h + (size_t)row * Hsz + (c8 - INsz));
  f32x4 v0 = *(const f32x4*)src;
  f32x4 v1 = *(const f32x4*)(src + 4);
  bf16x8 o;
  o[0] = (short)f2bf(v0[0]); o[1] = (short)f2bf(v0[1]);
  o[2] = (short)f2bf(v0[2]); o[3] = (short)f2bf(v0[3]);
  o[4] = (short)f2bf(v1[0]); o[5] = (short)f2bf(v1[1]);
  o[6] = (short)f2bf(v1[2]); o[7] = (short)f2bf(v1[3]);
  *(bf16x8*)(xh + (size_t)chunk * 8) = o;
}

// ---------------- transpose + convert: W[K][N] f32 -> WT[N][K] bf16 ----------------
// 64x64 tile, 256 threads. f32x4 global loads, bf16x8 (16B) global stores.
__global__ void transpose_conv_kernel(const float* __restrict__ W,
                                      unsigned short* __restrict__ WT,
                                      int K, int N) {
  __shared__ float tile[64][65];
  const size_t moff = (size_t)blockIdx.z * (size_t)K * N;
  int n0 = blockIdx.x * 64;
  int k0 = blockIdx.y * 64;
  int t = threadIdx.x;
  #pragma unroll
  for (int j = 0; j < 4; ++j) {
    int idx = j * 256 + t;              // 1024 chunks of f32x4
    int row = idx >> 4;                 // k-row within tile
    int c4 = (idx & 15) * 4;            // n-col within tile
    f32x4 v = *(const f32x4*)&W[moff + (size_t)(k0 + row) * N + n0 + c4];
    tile[row][c4 + 0] = v[0];
    tile[row][c4 + 1] = v[1];
    tile[row][c4 + 2] = v[2];
    tile[row][c4 + 3] = v[3];
  }
  __syncthreads();
  #pragma unroll
  for (int j = 0; j < 2; ++j) {
    int idx = j * 256 + t;              // 512 chunks of bf16x8
    int nr = idx >> 3;                  // n-row of output
    int kc = (idx & 7) * 8;             // k-col chunk
    bf16x8 o;
    #pragma unroll
    for (int i = 0; i < 8; ++i) o[i] = (short)f2bf(tile[kc + i][nr]);
    *(bf16x8*)&WT[moff + (size_t)(n0 + nr) * K + k0 + kc] = o;
  }
}

// ---------------- fused LSTM GEMM ----------------
// Block computes a 128x128 output tile. 4 waves, each 64x64 (4x4 frags of 16x16).
// LDS tiles: A [128][64] bf16, Bt [128][64] bf16 (B^T layout, rows = output cols).
// T2 XOR-swizzle (rule 21: linear gload_lds dest + pre-swizzled GLOBAL source +
// matching XOR on the ds_read address). Swizzle unit = 16B chunk, period 8 rows.
__device__ __forceinline__ void gemm_pass(
    const unsigned short* __restrict__ A,   // block A base (tile row 0, k 0), ld = Kxh
    const unsigned short* __restrict__ Bt,  // block B^T base (tile col 0, k 0)
    int ldb, int K,
    short* lA, short* lB,
    int tid, int lane, int wr, int wc,
    f32x4 (&acc)[4][4])
{
  const int il = lane & 15;
  const int kl = (lane >> 4) * 8;
  const int axor = (il & 7) << 3;          // read-side XOR (shorts); row&7 == il&7
  for (int k0 = 0; k0 < K; k0 += 64) {
    #pragma unroll
    for (int c = 0; c < 4; ++c) {
      int ch = c * 256 + tid;              // 1024 chunks of 16B = 16KB A tile
      int row = ch >> 3;
      int scc = (ch & 7) ^ (row & 7);      // source chunk pre-swizzle
      gload_lds16(A + (size_t)row * Kxh + k0 + scc * 8, lA + ch * 8);
    }
    #pragma unroll
    for (int c = 0; c < 4; ++c) {
      int ch = c * 256 + tid;
      int row = ch >> 3;
      int scc = (ch & 7) ^ (row & 7);
      gload_lds16(Bt + (size_t)row * ldb + k0 + scc * 8, lB + ch * 8);
    }
    __syncthreads();                        // drains vmcnt (compiler-inserted)
    #pragma unroll
    for (int ks = 0; ks < 2; ++ks) {
      bf16x8 a[4], b[4];
      #pragma unroll
      for (int m = 0; m < 4; ++m)
        a[m] = *(const bf16x8*)&lA[(wr * 64 + m * 16 + il) * 64 + ((ks * 32 + kl) ^ axor)];
      #pragma unroll
      for (int n = 0; n < 4; ++n)
        b[n] = *(const bf16x8*)&lB[(wc * 64 + n * 16 + il) * 64 + ((ks * 32 + kl) ^ axor)];
      #pragma unroll
      for (int m = 0; m < 4; ++m)
        #pragma unroll
        for (int n = 0; n < 4; ++n)
          acc[m][n] = __builtin_amdgcn_mfma_f32_16x16x32_bf16(a[m], b[n], acc[m][n], 0, 0, 0);
    }
    __syncthreads();
  }
}

__global__ __launch_bounds__(256, 2) void lstm_fused_kernel(
    const unsigned short* __restrict__ xh,    // [8192][3072] bf16
    const unsigned short* __restrict__ WgT,   // [4][2048][3072] bf16 (transposed)
    const unsigned short* __restrict__ WrT,   // [2048][1024] bf16 (transposed)
    const float* __restrict__ c_prev,         // [8192][2048]
    const float* __restrict__ b_gates,        // [4][2048]
    const float* __restrict__ b_res,          // [2048]
    float* __restrict__ h_out,
    float* __restrict__ c_out)
{
  __shared__ alignas(16) short lA[128 * 64];
  __shared__ alignas(16) short lB[128 * 64];
  const int tid = threadIdx.x;
  const int lane = tid & 63;
  const int wid = tid >> 6;
  const int wr = wid >> 1, wc = wid & 1;

  // XCD-aware swizzle (nwg=1024 % 8 == 0): each XCD gets a contiguous wg range.
  // Col-major block mapping: each XCD owns 2 col-blocks x 64 row-blocks, so its
  // B panel (256 cols x 3072 k x 2B = 1.5MB) stays L2-resident.
  const int orig = blockIdx.x;
  const int wg = (orig & 7) * 128 + (orig >> 3);
  const int bcol = (wg >> 6) * 128;           // 16 col blocks
  const int brow = (wg & 63) * 128;           // 64 row blocks

  const unsigned short* Ab = xh + (size_t)brow * Kxh;
  const int col0 = bcol + wc * 64 + (lane & 15);            // + n*16
  const int row0 = brow + wr * 64 + ((lane >> 4) << 2);     // + m*16 + r

  const f32x4 zf = {0.f, 0.f, 0.f, 0.f};
  f32x4 acc[4][4];
  f32x4 C[4][4];   // running cell state, later reused as h partial
  f32x4 I[4][4];

  // ---- pass 1: forget gate (g=1): C = sigmoid(f)*c_prev ----
  #pragma unroll
  for (int m = 0; m < 4; ++m)
    #pragma unroll
    for (int n = 0; n < 4; ++n) acc[m][n] = zf;
  gemm_pass(Ab, WgT + (size_t)(1 * Hsz + bcol) * Kxh, Kxh, Kxh, lA, lB, tid, lane, wr, wc, acc);
  #pragma unroll
  for (int n = 0; n < 4; ++n) {
    float bgn = b_gates[1 * Hsz + col0 + n * 16];
    #pragma unroll
    for (int m = 0; m < 4; ++m)
      #pragma unroll
      for (int r = 0; r < 4; ++r) {
        float f = fsigmoid(acc[m][n][r] + bgn);
        C[m][n][r] = f * c_prev[(size_t)(row0 + m * 16 + r) * Hsz + col0 + n * 16];
      }
  }

  // ---- pass 2: input gate (g=0): I = sigmoid(i) ----
  #pragma unroll
  for (int m = 0; m < 4; ++m)
    #pragma unroll
    for (int n = 0; n < 4; ++n) acc[m][n] = zf;
  gemm_pass(Ab, WgT + (size_t)(0 * Hsz + bcol) * Kxh, Kxh, Kxh, lA, lB, tid, lane, wr, wc, acc);
  #pragma unroll
  for (int n = 0; n < 4; ++n) {
    float bgn = b_gates[0 * Hsz + col0 + n * 16];
    #pragma unroll
    for (int m = 0; m < 4; ++m)
      #pragma unroll
      for (int r = 0; r < 4; ++r)
        I[m][n][r] = fsigmoid(acc[m][n][r] + bgn);
  }

  // ---- pass 3: c_hat (g=3): C += I*tanh(chat); write c_out; C <- tanh(C) ----
  #pragma unroll
  for (int m = 0; m < 4; ++m)
    #pragma unroll
    for (int n = 0; n < 4; ++n) acc[m][n] = zf;
  gemm_pass(Ab, WgT + (size_t)(3 * Hsz + bcol) * Kxh, Kxh, Kxh, lA, lB, tid, lane, wr, wc, acc);
  #pragma unroll
  for (int n = 0; n < 4; ++n) {
    float bgn = b_gates[3 * Hsz + col0 + n * 16];
    #pragma unroll
    for (int m = 0; m < 4; ++m)
      #pragma unroll
      for (int r = 0; r < 4; ++r) {
        float ct = C[m][n][r] + I[m][n][r] * ftanh(acc[m][n][r] + bgn);
        c_out[(size_t)(row0 + m * 16 + r) * Hsz + col0 + n * 16] = ct;
        C[m][n][r] = ftanh(ct);
      }
  }

  // ---- pass 4: output gate (g=2): C <- sigmoid(o)*tanh(c_t) ----
  #pragma unroll
  for (int m = 0; m < 4; ++m)
    #pragma unroll
    for (int n = 0; n < 4; ++n) acc[m][n] = zf;
  gemm_pass(Ab, WgT + (size_t)(2 * Hsz + bcol) * Kxh, Kxh, Kxh, lA, lB, tid, lane, wr, wc, acc);
  #pragma unroll
  for (int n = 0; n < 4; ++n) {
    float bgn = b_gates[2 * Hsz + col0 + n * 16];
    #pragma unroll
    for (int m = 0; m < 4; ++m)
      #pragma unroll
      for (int r = 0; r < 4; ++r)
        C[m][n][r] = fsigmoid(acc[m][n][r] + bgn) * C[m][n][r];
  }

  // ---- pass 5: residual (K=1024): h = o*tanh(c) + x@W_res + b_res ----
  #pragma unroll
  for (int m = 0; m < 4; ++m)
    #pragma unroll
    for (int n = 0; n < 4; ++n) acc[m][n] = zf;
  gemm_pass(Ab, WrT + (size_t)bcol * INsz, INsz, INsz, lA, lB, tid, lane, wr, wc, acc);
  #pragma unroll
  for (int n = 0; n < 4; ++n) {
    float brn = b_res[col0 + n * 16];
    #pragma unroll
    for (int m = 0; m < 4; ++m)
      #pragma unroll
      for (int r = 0; r < 4; ++r)
        h_out[(size_t)(row0 + m * 16 + r) * Hsz + col0 + n * 16] =
            C[m][n][r] + acc[m][n][r] + brn;
  }
}

extern "C" void kernel_launch(void* const* d_in, const int* in_sizes, int n_in,
                              void* d_out, int out_size, void* d_ws, size_t ws_size,
                              hipStream_t stream) {
  const float* x  = (const float*)d_in[0];
  const float* h  = (const float*)d_in[1];
  const float* c  = (const float*)d_in[2];
  const float* Wg = (const float*)d_in[3];
  const float* bg = (const float*)d_in[4];
  const float* Wr = (const float*)d_in[5];
  const float* br = (const float*)d_in[6];
  float* out = (float*)d_out;

  char* ws = (char*)d_ws;
  unsigned short* xh  = (unsigned short*)ws;                       // 50,331,648 B
  unsigned short* WgT = (unsigned short*)(ws + 50331648);          // 50,331,648 B
  unsigned short* WrT = (unsigned short*)(ws + 100663296);         //  4,194,304 B

  convert_xh_kernel<<<12288, 256, 0, stream>>>(x, h, xh);
  transpose_conv_kernel<<<dim3(32, 48, 4), 256, 0, stream>>>(Wg, WgT, Kxh, Hsz);
  transpose_conv_kernel<<<dim3(32, 16, 1), 256, 0, stream>>>(Wr, WrT, INsz, Hsz);

  lstm_fused_kernel<<<1024, 256, 0, stream>>>(
      xh, WgT, WrT, c, bg, br, out, out + (size_t)Bsz * Hsz);
}

// Round 3
// 911.580 us; speedup vs baseline: 1.1565x; 1.1086x over previous
//
#include <hip/hip_runtime.h>
#include <cstdint>
#include <cstddef>

#define Bsz 8192
#define INsz 1024
#define Hsz 2048
#define Kxh 3072   // IN + H

typedef __attribute__((ext_vector_type(8))) short bf16x8;
typedef __attribute__((ext_vector_type(4))) float f32x4;

__device__ __forceinline__ unsigned short f2bf(float f) {
  unsigned int u = __float_as_uint(f);
  u += 0x7FFFu + ((u >> 16) & 1u);   // round-to-nearest-even
  return (unsigned short)(u >> 16);
}
__device__ __forceinline__ float bf2f(short s) {
  return __uint_as_float((unsigned int)(unsigned short)s << 16);
}

__device__ __forceinline__ void gload_lds16(const void* g, void* l) {
  __builtin_amdgcn_global_load_lds(
      (const __attribute__((address_space(1))) void*)g,
      (__attribute__((address_space(3))) void*)l, 16, 0, 0);
}

__device__ __forceinline__ float fsigmoid(float x) { return 1.f / (1.f + __expf(-x)); }
__device__ __forceinline__ float ftanh(float x) {
  float ax = fabsf(x);
  float t = __expf(-2.f * ax);
  float r = (1.f - t) / (1.f + t);
  return copysignf(r, x);
}

// ---------------- conversion: xh = concat(x, h) as bf16 [8192][3072] ----------------
__global__ void convert_xh_kernel(const float* __restrict__ x,
                                  const float* __restrict__ h,
                                  unsigned short* __restrict__ xh) {
  int chunk = blockIdx.x * 256 + threadIdx.x;          // 3,145,728 chunks of 8
  int row = chunk / 384;
  int c8 = (chunk - row * 384) * 8;
  const float* src = (c8 < INsz) ? (x + (size_t)row * INsz + c8)
                                 : (h + (size_t)row * Hsz + (c8 - INsz));
  f32x4 v0 = *(const f32x4*)src;
  f32x4 v1 = *(const f32x4*)(src + 4);
  bf16x8 o;
  o[0] = (short)f2bf(v0[0]); o[1] = (short)f2bf(v0[1]);
  o[2] = (short)f2bf(v0[2]); o[3] = (short)f2bf(v0[3]);
  o[4] = (short)f2bf(v1[0]); o[5] = (short)f2bf(v1[1]);
  o[6] = (short)f2bf(v1[2]); o[7] = (short)f2bf(v1[3]);
  *(bf16x8*)(xh + (size_t)chunk * 8) = o;
}

// ---------------- transpose + convert: W[K][N] f32 -> WT[N][K] bf16 ----------------
__global__ void transpose_conv_kernel(const float* __restrict__ W,
                                      unsigned short* __restrict__ WT,
                                      int K, int N) {
  __shared__ float tile[64][65];
  const size_t moff = (size_t)blockIdx.z * (size_t)K * N;
  int n0 = blockIdx.x * 64;
  int k0 = blockIdx.y * 64;
  int t = threadIdx.x;
  #pragma unroll
  for (int j = 0; j < 4; ++j) {
    int idx = j * 256 + t;
    int row = idx >> 4;
    int c4 = (idx & 15) * 4;
    f32x4 v = *(const f32x4*)&W[moff + (size_t)(k0 + row) * N + n0 + c4];
    tile[row][c4 + 0] = v[0];
    tile[row][c4 + 1] = v[1];
    tile[row][c4 + 2] = v[2];
    tile[row][c4 + 3] = v[3];
  }
  __syncthreads();
  #pragma unroll
  for (int j = 0; j < 2; ++j) {
    int idx = j * 256 + t;
    int nr = idx >> 3;
    int kc = (idx & 7) * 8;
    bf16x8 o;
    #pragma unroll
    for (int i = 0; i < 8; ++i) o[i] = (short)f2bf(tile[kc + i][nr]);
    *(bf16x8*)&WT[moff + (size_t)(n0 + nr) * K + k0 + kc] = o;
  }
}

// ---------------- 256x256 8-wave GEMM, counted-vmcnt 4-phase schedule ----------------
// C = xh[8192][3072(or 1024)] @ planes of B^T. Planes 0-3: gates (bf16 out, K=3072),
// plane 4: residual (f32 out to d_out h region, K=1024).
// LDS: per K-tile (BK=64) split into k-sections s=0,1 (32 k each). Half = one matrix
// x one ksec = 256 rows x 32 k x 2B = 16KB = 512 thr x 16B x 2 issues.
// Swizzle: 16B chunk c of row r stored at position c ^ (r&3) ^ ((r>>2)&3) (involution,
// applied on pre-swizzled global source per rule 21; ds_read applies same XOR).
// vmcnt(4) at ksec boundaries only (never 0): FIFO per wave =
// [A_s0(2), B_s0(2), A_s1(2), B_s1(2)] per tile; at each boundary the oldest 4
// (the needed halves) complete, newest 4 stay in flight.
__device__ __forceinline__ int lds_chunk(int row, int c) {
  return (row << 2) | (c ^ ((row & 3) ^ ((row >> 2) & 3)));
}

__global__ __launch_bounds__(512, 2) void gemm_gates_kernel(
    const unsigned short* __restrict__ xh,    // [8192][3072] bf16
    const unsigned short* __restrict__ WgT,   // [4][2048][3072] bf16
    const unsigned short* __restrict__ WrT,   // [2048][1024] bf16
    unsigned short* __restrict__ gates,       // [4][8192][2048] bf16 (pre-activation)
    float* __restrict__ res_out)              // [8192][2048] f32
{
  __shared__ short lA[2][2][8192];   // [dbuf][ksec][256 rows x 32 shorts]
  __shared__ short lB[2][2][8192];
  const int tid = threadIdx.x;
  const int lane = tid & 63;
  const int wid = tid >> 6;
  const int wm = wid >> 2, wn = wid & 3;      // 2M x 4N wave grid; wave out 128x64
  const int il = lane & 15, kl = lane >> 4;

  // XCD-aware mapping: nwg=1280, xcd = orig%8 owns 5 col-tiles {xcd, xcd+8, ..., xcd+32}
  // x 32 row-tiles (row-fastest) -> B col panel (1.5MB) L2-hot; res cols spread evenly.
  const int orig = blockIdx.x;
  const int xcd = orig & 7;
  const int idx = orig >> 3;
  const int bcol_t = ((idx >> 5) << 3) + xcd;   // 0..39
  const int brow_t = idx & 31;
  const int brow = brow_t * 256;
  const int bcol = bcol_t * 256;
  const int plane = bcol >> 11;                 // 0..4
  const int pcol = bcol & 2047;

  const unsigned short* Ag = xh + (size_t)brow * Kxh;
  const unsigned short* Bg;
  int ldb, K;
  if (plane < 4) { Bg = WgT + ((size_t)plane * Hsz + pcol) * Kxh; ldb = Kxh; K = Kxh; }
  else           { Bg = WrT + (size_t)pcol * INsz;                ldb = INsz; K = INsz; }
  const int nt = K >> 6;

  // per-thread stage components (issue 0: rows 0-127, issue 1: rows 128-255)
  const int r0 = tid >> 2;
  const int r1 = r0 + 128;
  const int c0 = (tid & 3) ^ ((r0 & 3) ^ ((r0 >> 2) & 3));
  const int c1 = (tid & 3) ^ ((r1 & 3) ^ ((r1 >> 2) & 3));
  const size_t a_off0 = (size_t)r0 * Kxh + c0 * 8;
  const size_t a_off1 = (size_t)r1 * Kxh + c1 * 8;
  const size_t b_off0 = (size_t)r0 * (size_t)ldb + c0 * 8;
  const size_t b_off1 = (size_t)r1 * (size_t)ldb + c1 * 8;
  const int lds_t0 = tid * 8;
  const int lds_t1 = (tid + 512) * 8;

  const int a_row = wm * 128 + il;
  const int b_row = wn * 64 + il;

  f32x4 acc[8][4];
  #pragma unroll
  for (int m = 0; m < 8; ++m)
    #pragma unroll
    for (int n = 0; n < 4; ++n) acc[m][n] = f32x4{0.f, 0.f, 0.f, 0.f};

  // prologue: tile 0, FIFO order A_s0 B_s0 A_s1 B_s1
  gload_lds16(Ag + a_off0,      &lA[0][0][lds_t0]);
  gload_lds16(Ag + a_off1,      &lA[0][0][lds_t1]);
  gload_lds16(Bg + b_off0,      &lB[0][0][lds_t0]);
  gload_lds16(Bg + b_off1,      &lB[0][0][lds_t1]);
  gload_lds16(Ag + a_off0 + 32, &lA[0][1][lds_t0]);
  gload_lds16(Ag + a_off1 + 32, &lA[0][1][lds_t1]);
  gload_lds16(Bg + b_off0 + 32, &lB[0][1][lds_t0]);
  gload_lds16(Bg + b_off1 + 32, &lB[0][1][lds_t1]);

  for (int t = 0; t < nt; ++t) {
    const int cur = t & 1, nxt = cur ^ 1;
    const bool pf = (t + 1) < nt;
    const int kpre = (t + 1) << 6;        // shorts offset of next tile
    bf16x8 bq[4], af[4];

    // ---- phase 0: ksec0, m 0-3 ----
    __builtin_amdgcn_sched_barrier(0);
    asm volatile("s_waitcnt vmcnt(4)" ::: "memory");
    asm volatile("s_barrier" ::: "memory");
    __builtin_amdgcn_sched_barrier(0);
    #pragma unroll
    for (int n = 0; n < 4; ++n)
      bq[n] = *(const bf16x8*)&lB[cur][0][lds_chunk(b_row + n * 16, kl) * 8];
    #pragma unroll
    for (int m = 0; m < 4; ++m)
      af[m] = *(const bf16x8*)&lA[cur][0][lds_chunk(a_row + m * 16, kl) * 8];
    if (pf) {
      gload_lds16(Ag + a_off0 + kpre, &lA[nxt][0][lds_t0]);
      gload_lds16(Ag + a_off1 + kpre, &lA[nxt][0][lds_t1]);
    }
    __builtin_amdgcn_s_setprio(1);
    #pragma unroll
    for (int m = 0; m < 4; ++m)
      #pragma unroll
      for (int n = 0; n < 4; ++n)
        acc[m][n] = __builtin_amdgcn_mfma_f32_16x16x32_bf16(af[m], bq[n], acc[m][n], 0, 0, 0);
    __builtin_amdgcn_s_setprio(0);

    // ---- phase 1: ksec0, m 4-7 ----
    #pragma unroll
    for (int m = 0; m < 4; ++m)
      af[m] = *(const bf16x8*)&lA[cur][0][lds_chunk(a_row + (m + 4) * 16, kl) * 8];
    if (pf) {
      gload_lds16(Bg + b_off0 + kpre, &lB[nxt][0][lds_t0]);
      gload_lds16(Bg + b_off1 + kpre, &lB[nxt][0][lds_t1]);
    }
    __builtin_amdgcn_s_setprio(1);
    #pragma unroll
    for (int m = 0; m < 4; ++m)
      #pragma unroll
      for (int n = 0; n < 4; ++n)
        acc[m + 4][n] = __builtin_amdgcn_mfma_f32_16x16x32_bf16(af[m], bq[n], acc[m + 4][n], 0, 0, 0);
    __builtin_amdgcn_s_setprio(0);

    // ---- phase 2: ksec1, m 0-3 ----
    __builtin_amdgcn_sched_barrier(0);
    asm volatile("s_waitcnt vmcnt(4)" ::: "memory");
    asm volatile("s_barrier" ::: "memory");
    __builtin_amdgcn_sched_barrier(0);
    #pragma unroll
    for (int n = 0; n < 4; ++n)
      bq[n] = *(const bf16x8*)&lB[cur][1][lds_chunk(b_row + n * 16, kl) * 8];
    #pragma unroll
    for (int m = 0; m < 4; ++m)
      af[m] = *(const bf16x8*)&lA[cur][1][lds_chunk(a_row + m * 16, kl) * 8];
    if (pf) {
      gload_lds16(Ag + a_off0 + kpre + 32, &lA[nxt][1][lds_t0]);
      gload_lds16(Ag + a_off1 + kpre + 32, &lA[nxt][1][lds_t1]);
    }
    __builtin_amdgcn_s_setprio(1);
    #pragma unroll
    for (int m = 0; m < 4; ++m)
      #pragma unroll
      for (int n = 0; n < 4; ++n)
        acc[m][n] = __builtin_amdgcn_mfma_f32_16x16x32_bf16(af[m], bq[n], acc[m][n], 0, 0, 0);
    __builtin_amdgcn_s_setprio(0);

    // ---- phase 3: ksec1, m 4-7 ----
    #pragma unroll
    for (int m = 0; m < 4; ++m)
      af[m] = *(const bf16x8*)&lA[cur][1][lds_chunk(a_row + (m + 4) * 16, kl) * 8];
    if (pf) {
      gload_lds16(Bg + b_off0 + kpre + 32, &lB[nxt][1][lds_t0]);
      gload_lds16(Bg + b_off1 + kpre + 32, &lB[nxt][1][lds_t1]);
    }
    __builtin_amdgcn_s_setprio(1);
    #pragma unroll
    for (int m = 0; m < 4; ++m)
      #pragma unroll
      for (int n = 0; n < 4; ++n)
        acc[m + 4][n] = __builtin_amdgcn_mfma_f32_16x16x32_bf16(af[m], bq[n], acc[m + 4][n], 0, 0, 0);
    __builtin_amdgcn_s_setprio(0);
  }

  // ---- C write ----
  const int g_row0 = brow + wm * 128 + kl * 4;   // + m*16 + r
  if (plane < 4) {
    unsigned short* gp = gates + (size_t)plane * ((size_t)Bsz * Hsz);
    #pragma unroll
    for (int m = 0; m < 8; ++m)
      #pragma unroll
      for (int n = 0; n < 4; ++n) {
        int col = pcol + wn * 64 + n * 16 + il;
        #pragma unroll
        for (int r = 0; r < 4; ++r)
          gp[(size_t)(g_row0 + m * 16 + r) * Hsz + col] = f2bf(acc[m][n][r]);
      }
  } else {
    #pragma unroll
    for (int m = 0; m < 8; ++m)
      #pragma unroll
      for (int n = 0; n < 4; ++n) {
        int col = pcol + wn * 64 + n * 16 + il;
        #pragma unroll
        for (int r = 0; r < 4; ++r)
          res_out[(size_t)(g_row0 + m * 16 + r) * Hsz + col] = acc[m][n][r];
      }
  }
}

// ---------------- elementwise epilogue ----------------
__global__ __launch_bounds__(256) void lstm_epilogue_kernel(
    const unsigned short* __restrict__ gates,  // [4][8192][2048] bf16, order i,f,o,chat
    const float* __restrict__ c_prev,
    const float* __restrict__ b_gates,
    const float* __restrict__ b_res,
    float* __restrict__ h_out,                 // holds res on entry
    float* __restrict__ c_out)
{
  const size_t plane = (size_t)Bsz * Hsz;
  int idx = blockIdx.x * 256 + threadIdx.x;    // 2,097,152 chunks of 8
  size_t base = (size_t)idx * 8;
  int hcol = (idx & 255) * 8;
  bf16x8 gi = *(const bf16x8*)(gates + 0 * plane + base);
  bf16x8 gf = *(const bf16x8*)(gates + 1 * plane + base);
  bf16x8 go = *(const bf16x8*)(gates + 2 * plane + base);
  bf16x8 gc = *(const bf16x8*)(gates + 3 * plane + base);
  f32x4 cp0 = *(const f32x4*)(c_prev + base);
  f32x4 cp1 = *(const f32x4*)(c_prev + base + 4);
  f32x4 rs0 = *(const f32x4*)(h_out + base);
  f32x4 rs1 = *(const f32x4*)(h_out + base + 4);
  f32x4 h0, h1, c0, c1;
  #pragma unroll
  for (int j = 0; j < 8; ++j) {
    float ig = fsigmoid(bf2f(gi[j]) + b_gates[0 * Hsz + hcol + j]);
    float fg = fsigmoid(bf2f(gf[j]) + b_gates[1 * Hsz + hcol + j]);
    float og = fsigmoid(bf2f(go[j]) + b_gates[2 * Hsz + hcol + j]);
    float ch = ftanh  (bf2f(gc[j]) + b_gates[3 * Hsz + hcol + j]);
    float cp = (j < 4) ? cp0[j] : cp1[j - 4];
    float rs = ((j < 4) ? rs0[j] : rs1[j - 4]) + b_res[hcol + j];
    float ct = fg * cp + ig * ch;
    float ht = og * ftanh(ct) + rs;
    if (j < 4) { c0[j] = ct; h0[j] = ht; } else { c1[j - 4] = ct; h1[j - 4] = ht; }
  }
  *(f32x4*)(h_out + base)     = h0;
  *(f32x4*)(h_out + base + 4) = h1;
  *(f32x4*)(c_out + base)     = c0;
  *(f32x4*)(c_out + base + 4) = c1;
}

extern "C" void kernel_launch(void* const* d_in, const int* in_sizes, int n_in,
                              void* d_out, int out_size, void* d_ws, size_t ws_size,
                              hipStream_t stream) {
  const float* x  = (const float*)d_in[0];
  const float* h  = (const float*)d_in[1];
  const float* c  = (const float*)d_in[2];
  const float* Wg = (const float*)d_in[3];
  const float* bg = (const float*)d_in[4];
  const float* Wr = (const float*)d_in[5];
  const float* br = (const float*)d_in[6];
  float* out = (float*)d_out;

  char* ws = (char*)d_ws;
  unsigned short* xh    = (unsigned short*)ws;                    //  50,331,648 B
  unsigned short* WgT   = (unsigned short*)(ws + 50331648);       //  50,331,648 B
  unsigned short* WrT   = (unsigned short*)(ws + 100663296);      //   4,194,304 B
  unsigned short* gates = (unsigned short*)(ws + 104857600);      // 134,217,728 B (total 239MB)

  convert_xh_kernel<<<12288, 256, 0, stream>>>(x, h, xh);
  transpose_conv_kernel<<<dim3(32, 48, 4), 256, 0, stream>>>(Wg, WgT, Kxh, Hsz);
  transpose_conv_kernel<<<dim3(32, 16, 1), 256, 0, stream>>>(Wr, WrT, INsz, Hsz);

  gemm_gates_kernel<<<1280, 512, 0, stream>>>(xh, WgT, WrT, gates, out);

  lstm_epilogue_kernel<<<8192, 256, 0, stream>>>(
      gates, c, bg, br, out, out + (size_t)Bsz * Hsz);
}